// Round 1
// baseline (1639.513 us; speedup 1.0000x reference)
//
#include <hip/hip_runtime.h>
#include <hip/hip_bf16.h>
#include <math.h>

#define DDIM 1024
#define EPSV 1e-8f

// ---------------- norms: one wave (64 lanes) per row ----------------
__global__ void norms_kernel(const float* __restrict__ X, float* __restrict__ out, int rows) {
  int gwave = (blockIdx.x * blockDim.x + threadIdx.x) >> 6;
  int lane = threadIdx.x & 63;
  int nwaves = (gridDim.x * blockDim.x) >> 6;
  for (int r = gwave; r < rows; r += nwaves) {
    const float4* p = (const float4*)(X + (size_t)r * DDIM);
    float s = 0.f;
#pragma unroll
    for (int j = 0; j < DDIM / 4 / 64; ++j) {
      float4 v = p[lane + j * 64];
      s += v.x * v.x + v.y * v.y + v.z * v.z + v.w * v.w;
    }
#pragma unroll
    for (int o = 32; o > 0; o >>= 1) s += __shfl_down(s, o, 64);
    if (lane == 0) out[r] = sqrtf(s);
  }
}

// ---------------- 128x128 fp32 GEMM (raw dots into sims slab) ----------------
__global__ __launch_bounds__(256) void gemm_slab(
    const float* __restrict__ Q, const float* __restrict__ M,
    float* __restrict__ sims, int n_base, int Ns, int N) {
  __shared__ float As[8][128];
  __shared__ float Bs[8][128];
  const int tid = threadIdx.x;
  const int tx = tid & 15;
  const int ty = tid >> 4;
  const int q0 = blockIdx.y * 128;
  const int nloc0 = blockIdx.x * 128;
  const int ar = tid >> 1;         // 0..127 row within tile
  const int ac = (tid & 1) * 4;    // 0 or 4 (column within BK=8)
  const float* Ap = Q + (size_t)(q0 + ar) * DDIM + ac;
  int brow = n_base + nloc0 + ar;
  bool bvalid = brow < N;
  const float* Bp = M + (size_t)(bvalid ? brow : 0) * DDIM + ac;
  float acc[8][8] = {};
  for (int k0 = 0; k0 < DDIM; k0 += 8) {
    float4 av = *(const float4*)(Ap + k0);
    float4 bv = bvalid ? *(const float4*)(Bp + k0) : make_float4(0.f, 0.f, 0.f, 0.f);
    __syncthreads();
    As[ac + 0][ar] = av.x; As[ac + 1][ar] = av.y; As[ac + 2][ar] = av.z; As[ac + 3][ar] = av.w;
    Bs[ac + 0][ar] = bv.x; Bs[ac + 1][ar] = bv.y; Bs[ac + 2][ar] = bv.z; Bs[ac + 3][ar] = bv.w;
    __syncthreads();
#pragma unroll
    for (int k = 0; k < 8; ++k) {
      float a[8], b[8];
      *(float4*)&a[0] = *(const float4*)&As[k][ty * 8];
      *(float4*)&a[4] = *(const float4*)&As[k][ty * 8 + 4];
      *(float4*)&b[0] = *(const float4*)&Bs[k][tx * 8];
      *(float4*)&b[4] = *(const float4*)&Bs[k][tx * 8 + 4];
#pragma unroll
      for (int i = 0; i < 8; ++i)
#pragma unroll
        for (int j = 0; j < 8; ++j)
          acc[i][j] = fmaf(a[i], b[j], acc[i][j]);
    }
  }
#pragma unroll
  for (int i = 0; i < 8; ++i) {
    float* dst = sims + (size_t)(q0 + ty * 8 + i) * Ns + nloc0 + tx * 8;
    *(float4*)dst = make_float4(acc[i][0], acc[i][1], acc[i][2], acc[i][3]);
    *((float4*)dst + 1) = make_float4(acc[i][4], acc[i][5], acc[i][6], acc[i][7]);
  }
}

// ---------------- top-k helpers ----------------
__device__ __forceinline__ bool better(float v1, int i1, float v2, int i2) {
  return v1 > v2 || (v1 == v2 && i1 < i2);
}

__device__ __forceinline__ void topk_insert16(float (&tv)[16], int (&ti)[16], float v, int idx) {
  if (better(v, idx, tv[15], ti[15])) {
    tv[15] = v; ti[15] = idx;
#pragma unroll
    for (int j = 15; j > 0; --j) {
      if (better(tv[j], ti[j], tv[j - 1], ti[j - 1])) {
        float fv = tv[j]; tv[j] = tv[j - 1]; tv[j - 1] = fv;
        int ii = ti[j]; ti[j] = ti[j - 1]; ti[j - 1] = ii;
      }
    }
  }
}

// 16-round block tournament over per-thread sorted top-16 lists (blockDim=256).
template <typename F>
__device__ __forceinline__ void block_topk_16(float (&tv)[16], int (&ti)[16], F&& emit) {
  __shared__ float s_v[4];
  __shared__ int s_i[4];
  __shared__ int s_t[4];
  __shared__ float s_wv;
  __shared__ int s_wi;
  __shared__ int s_wt;
  for (int r = 0; r < 16; ++r) {
    float v = tv[0];
    int idx = ti[0];
    int src = threadIdx.x;
#pragma unroll
    for (int o = 32; o > 0; o >>= 1) {
      float ov = __shfl_down(v, o, 64);
      int oi = __shfl_down(idx, o, 64);
      int os = __shfl_down(src, o, 64);
      if (better(ov, oi, v, idx)) { v = ov; idx = oi; src = os; }
    }
    int lane = threadIdx.x & 63, w = threadIdx.x >> 6;
    if (lane == 0) { s_v[w] = v; s_i[w] = idx; s_t[w] = src; }
    __syncthreads();
    if (threadIdx.x == 0) {
      float bv = s_v[0]; int bi = s_i[0]; int bt = s_t[0];
      for (int w2 = 1; w2 < 4; ++w2)
        if (better(s_v[w2], s_i[w2], bv, bi)) { bv = s_v[w2]; bi = s_i[w2]; bt = s_t[w2]; }
      s_wv = bv; s_wi = bi; s_wt = bt;
    }
    __syncthreads();
    if (threadIdx.x == s_wt) {
#pragma unroll
      for (int j = 0; j < 15; ++j) { tv[j] = tv[j + 1]; ti[j] = ti[j + 1]; }
      tv[15] = -INFINITY; ti[15] = 0x7fffffff;
    }
    if (threadIdx.x == 0) emit(r, s_wv, s_wi);
    __syncthreads();
  }
}

// ---------------- per-slab selection: one block per query ----------------
__global__ __launch_bounds__(256) void select_slab(
    const float* __restrict__ sims, const float* __restrict__ mn, const float* __restrict__ qn,
    float2* __restrict__ cand, int n_base, int Ns, int N, int B, int s) {
  int b = blockIdx.x;
  float q = qn[b];
  float tv[16]; int ti[16];
#pragma unroll
  for (int j = 0; j < 16; ++j) { tv[j] = -INFINITY; ti[j] = 0x7fffffff; }
  const float* row = sims + (size_t)b * Ns;
  int lim = N - n_base;
  if (lim > Ns) lim = Ns;
  for (int j = threadIdx.x; j < lim; j += 256) {
    float dot = row[j];
    int n = n_base + j;
    float den = fmaxf(q * mn[n], EPSV);
    topk_insert16(tv, ti, dot / den, n);
  }
  float2* base = cand + ((size_t)s * B + b) * 16;
  block_topk_16(tv, ti, [&](int r, float v, int i) {
    base[r] = make_float2(v, (float)i);
  });
}

// ---------------- final merge across slabs ----------------
__global__ __launch_bounds__(256) void merge_topk(
    const float2* __restrict__ cand, float* __restrict__ out, int B, int S) {
  int b = blockIdx.x;
  float tv[16]; int ti[16];
#pragma unroll
  for (int j = 0; j < 16; ++j) { tv[j] = -INFINITY; ti[j] = 0x7fffffff; }
  int total = S * 16;
  for (int e = threadIdx.x; e < total; e += 256) {
    int s = e >> 4, r = e & 15;
    float2 c = cand[((size_t)s * B + b) * 16 + r];
    int idx = (c.x == -INFINITY) ? 0x7fffffff : (int)c.y;
    topk_insert16(tv, ti, c.x, idx);
  }
  float* ov = out + (size_t)b * 16;
  float* oi = out + (size_t)B * 16 + (size_t)b * 16;
  block_topk_16(tv, ti, [&](int r, float v, int i) {
    ov[r] = v;
    oi[r] = (float)i;
  });
}

extern "C" void kernel_launch(void* const* d_in, const int* in_sizes, int n_in,
                              void* d_out, int out_size, void* d_ws, size_t ws_size,
                              hipStream_t stream) {
  const float* Q = (const float*)d_in[0];
  const float* M = (const float*)d_in[1];
  int B = in_sizes[0] / DDIM;
  int N = in_sizes[1] / DDIM;
  float* out = (float*)d_out;

  char* w = (char*)d_ws;
  size_t mn_bytes = (((size_t)N * 4) + 255) & ~(size_t)255;
  size_t qn_bytes = (((size_t)B * 4) + 255) & ~(size_t)255;
  const int S_MAX = 64;
  size_t cand_bytes = (size_t)S_MAX * B * 16 * sizeof(float2);
  float* mn = (float*)w;
  float* qn = (float*)(w + mn_bytes);
  float2* cand = (float2*)(w + mn_bytes + qn_bytes);
  float* sims = (float*)(w + mn_bytes + qn_bytes + cand_bytes);

  size_t fixed = mn_bytes + qn_bytes + cand_bytes;
  size_t avail = ws_size > fixed ? ws_size - fixed : 0;
  long Ns = (long)(avail / ((size_t)B * 4));
  Ns = (Ns / 128) * 128;
  long Npad = (((long)N + 127) / 128) * 128;
  if (Ns > Npad) Ns = Npad;
  long minNs = (Npad + S_MAX - 1) / S_MAX;
  minNs = ((minNs + 127) / 128) * 128;
  if (Ns < minNs) Ns = minNs;  // assume ws_size >= ~5 MB
  int S = (int)(((long)N + Ns - 1) / Ns);

  norms_kernel<<<(N + 3) / 4, 256, 0, stream>>>(M, mn, N);
  norms_kernel<<<(B + 3) / 4, 256, 0, stream>>>(Q, qn, B);

  for (int s = 0; s < S; ++s) {
    int n_base = (int)((long)s * Ns);
    dim3 ggrid((unsigned)(Ns / 128), (unsigned)(B / 128));
    gemm_slab<<<ggrid, 256, 0, stream>>>(Q, M, sims, n_base, (int)Ns, N);
    select_slab<<<B, 256, 0, stream>>>(sims, mn, qn, cand, n_base, (int)Ns, N, B, s);
  }
  merge_topk<<<B, 256, 0, stream>>>(cand, out, B, S);
}

// Round 2
// 745.492 us; speedup vs baseline: 2.1992x; 2.1992x over previous
//
#include <hip/hip_runtime.h>
#include <math.h>

#define DDIM 1024
#define BQ 256
#define EPSV 1e-8f
#define CH 4
#define TPC 32
#define NCAND (CH * TPC)

typedef short bf16x8 __attribute__((ext_vector_type(8)));
typedef float f32x4 __attribute__((ext_vector_type(4)));

__device__ __forceinline__ unsigned short f2bf(float x) {
  union { float f; unsigned int u; } v;
  v.f = x;
  unsigned int lsb = (v.u >> 16) & 1u;
  v.u += 0x7fffu + lsb;  // round-to-nearest-even
  return (unsigned short)(v.u >> 16);
}
__device__ __forceinline__ float bf2f(unsigned short b) {
  union { unsigned int u; float f; } v;
  v.u = ((unsigned int)b) << 16;
  return v.f;
}

#define ASYNC_CP16(gp, lp)                                                     \
  __builtin_amdgcn_global_load_lds(                                            \
      (const __attribute__((address_space(1))) unsigned int*)(const void*)(gp),\
      (__attribute__((address_space(3))) unsigned int*)(lp), 16, 0, 0)

// ---------------- prep: Q fp32 -> bf16, qn ----------------
__global__ __launch_bounds__(256) void prep_q(const float* __restrict__ Q,
                                              unsigned short* __restrict__ Qb,
                                              float* __restrict__ qn) {
  int wave = threadIdx.x >> 6, lane = threadIdx.x & 63;
  int q = blockIdx.x * 4 + wave;
  const float4* src = (const float4*)(Q + (size_t)q * DDIM);
  unsigned short* dst = Qb + (size_t)q * DDIM;
  float s = 0.f;
#pragma unroll
  for (int t = 0; t < 4; ++t) {
    float4 v = src[t * 64 + lane];
    s += v.x * v.x + v.y * v.y + v.z * v.z + v.w * v.w;
    ushort4 o;
    o.x = f2bf(v.x); o.y = f2bf(v.y); o.z = f2bf(v.z); o.w = f2bf(v.w);
    *(ushort4*)(dst + t * 256 + lane * 4) = o;
  }
#pragma unroll
  for (int o = 32; o > 0; o >>= 1) s += __shfl_down(s, o, 64);
  if (lane == 0) qn[q] = sqrtf(s);
}

// ---------------- MFMA GEMM: all 256 q x 64 n per block ----------------
__global__ __launch_bounds__(256) void gemm_topk(
    const float* __restrict__ M, const unsigned short* __restrict__ Qb,
    unsigned short* __restrict__ sims, float* __restrict__ rmn,
    int N, int Npitch) {
  __shared__ unsigned short Qs[256 * 32];  // [q][k], row = 32 bf16 = 64 B
  __shared__ unsigned short Ms[64 * 32];   // [n][k]
  const int tid = threadIdx.x;
  const int wave = tid >> 6, lane = tid & 63;
  const int quad = lane >> 4, l15 = lane & 15;
  const int n0 = blockIdx.x * 64;

  const int mrow = tid >> 2;    // 0..63
  const int mchunk = tid & 3;   // 0..3, 8 floats each
  const bool mvalid = (n0 + mrow) < N;
  const float* mptr = M + (size_t)(mvalid ? (n0 + mrow) : 0) * DDIM + mchunk * 8;

  f32x4 acc[4][4];
#pragma unroll
  for (int i = 0; i < 4; ++i)
#pragma unroll
    for (int j = 0; j < 4; ++j) acc[i][j] = (f32x4){0.f, 0.f, 0.f, 0.f};
  float sumsq = 0.f;

  for (int k0 = 0; k0 < DDIM; k0 += 32) {
    float4 m0, m1;
    if (mvalid) {
      m0 = *(const float4*)(mptr + k0);
      m1 = *(const float4*)(mptr + k0 + 4);
    } else {
      m0 = make_float4(0.f, 0.f, 0.f, 0.f);
      m1 = m0;
    }
    __syncthreads();  // previous iteration's MFMA reads done
    // Q tile async global->LDS (Qb already bf16). 4 rounds x 4 waves x 16 rows.
#pragma unroll
    for (int r = 0; r < 4; ++r) {
      int row0 = r * 64 + wave * 16;  // wave-uniform
      const unsigned short* g =
          Qb + (size_t)(row0 + (lane >> 2)) * DDIM + k0 + (lane & 3) * 8;
      ASYNC_CP16(g, &Qs[row0 * 32]);
    }
    // M tile: convert + sumsq + LDS write (16 B)
    sumsq += m0.x * m0.x + m0.y * m0.y + m0.z * m0.z + m0.w * m0.w +
             m1.x * m1.x + m1.y * m1.y + m1.z * m1.z + m1.w * m1.w;
    uint4 packed;
    packed.x = (unsigned int)f2bf(m0.x) | ((unsigned int)f2bf(m0.y) << 16);
    packed.y = (unsigned int)f2bf(m0.z) | ((unsigned int)f2bf(m0.w) << 16);
    packed.z = (unsigned int)f2bf(m1.x) | ((unsigned int)f2bf(m1.y) << 16);
    packed.w = (unsigned int)f2bf(m1.z) | ((unsigned int)f2bf(m1.w) << 16);
    *(uint4*)&Ms[mrow * 32 + mchunk * 8] = packed;
    __syncthreads();
    // MFMA: wave handles q in [wave*64, wave*64+64), n in [0,64)
    bf16x8 afr[4], bfr[4];
#pragma unroll
    for (int i = 0; i < 4; ++i)
      afr[i] = *(const bf16x8*)&Qs[(wave * 64 + i * 16 + l15) * 32 + quad * 8];
#pragma unroll
    for (int j = 0; j < 4; ++j)
      bfr[j] = *(const bf16x8*)&Ms[(j * 16 + l15) * 32 + quad * 8];
#pragma unroll
    for (int i = 0; i < 4; ++i)
#pragma unroll
      for (int j = 0; j < 4; ++j)
        acc[i][j] = __builtin_amdgcn_mfma_f32_16x16x32_bf16(afr[i], bfr[j],
                                                            acc[i][j], 0, 0, 0);
  }

  // 1/||m|| for this block's 64 rows (exact fp32 sums from staging data)
  float s = sumsq;
  s += __shfl_xor(s, 1, 64);
  s += __shfl_xor(s, 2, 64);
  if (mchunk == 0) rmn[n0 + mrow] = (s > 0.f) ? rsqrtf(s) : 0.f;

  // store bf16 dots
#pragma unroll
  for (int i = 0; i < 4; ++i)
#pragma unroll
    for (int j = 0; j < 4; ++j)
#pragma unroll
      for (int r = 0; r < 4; ++r) {
        int q = wave * 64 + i * 16 + quad * 4 + r;
        int n = n0 + j * 16 + l15;
        sims[(size_t)q * Npitch + n] = f2bf(acc[i][j][r]);
      }
}

// ---------------- helpers ----------------
__device__ __forceinline__ bool better(float v1, int i1, float v2, int i2) {
  return v1 > v2 || (v1 == v2 && i1 < i2);
}

template <int L>
__device__ __forceinline__ void insert_topL(float (&tv)[L], int (&ti)[L],
                                            float v, int idx) {
  if (v > tv[L - 1] || (v == tv[L - 1] && idx < ti[L - 1])) {
    tv[L - 1] = v; ti[L - 1] = idx;
#pragma unroll
    for (int j = L - 1; j > 0; --j) {
      if (better(tv[j], ti[j], tv[j - 1], ti[j - 1])) {
        float fv = tv[j]; tv[j] = tv[j - 1]; tv[j - 1] = fv;
        int ii = ti[j]; ti[j] = ti[j - 1]; ti[j - 1] = ii;
      }
    }
  }
}

// block tournament (blockDim=256): extract `rounds` best entries across
// per-thread sorted lists of length L.
template <int L, typename F>
__device__ __forceinline__ void block_extract(float (&tv)[L], int (&ti)[L],
                                              int rounds, F&& emit) {
  __shared__ float s_v[4];
  __shared__ int s_i[4];
  __shared__ int s_t[4];
  __shared__ float s_wv;
  __shared__ int s_wi;
  __shared__ int s_wt;
  for (int r = 0; r < rounds; ++r) {
    float v = tv[0];
    int idx = ti[0];
    int src = threadIdx.x;
#pragma unroll
    for (int o = 32; o > 0; o >>= 1) {
      float ov = __shfl_down(v, o, 64);
      int oi = __shfl_down(idx, o, 64);
      int os = __shfl_down(src, o, 64);
      if (better(ov, oi, v, idx)) { v = ov; idx = oi; src = os; }
    }
    int lane = threadIdx.x & 63, w = threadIdx.x >> 6;
    if (lane == 0) { s_v[w] = v; s_i[w] = idx; s_t[w] = src; }
    __syncthreads();
    if (threadIdx.x == 0) {
      float bv = s_v[0]; int bi = s_i[0]; int bt = s_t[0];
      for (int w2 = 1; w2 < 4; ++w2)
        if (better(s_v[w2], s_i[w2], bv, bi)) { bv = s_v[w2]; bi = s_i[w2]; bt = s_t[w2]; }
      s_wv = bv; s_wi = bi; s_wt = bt;
    }
    __syncthreads();
    if (threadIdx.x == s_wt) {
#pragma unroll
      for (int j = 0; j < L - 1; ++j) { tv[j] = tv[j + 1]; ti[j] = ti[j + 1]; }
      tv[L - 1] = -INFINITY; ti[L - 1] = 0x7fffffff;
    }
    if (threadIdx.x == 0) emit(r, s_wv, s_wi);
    __syncthreads();
  }
}

// ---------------- selection: per (q, chunk) top-32 by bf16 cos ----------------
__global__ __launch_bounds__(256) void select_chunks(
    const unsigned short* __restrict__ sims, const float* __restrict__ rmn,
    int* __restrict__ cand, int N, int Npitch, int Nc) {
  int q = blockIdx.y;
  int c = blockIdx.x;
  int start = c * Nc;
  int end = start + Nc;
  if (end > N) end = N;
  float tv[8]; int ti[8];
#pragma unroll
  for (int j = 0; j < 8; ++j) { tv[j] = -INFINITY; ti[j] = 0x7fffffff; }
  const unsigned short* row = sims + (size_t)q * Npitch;
  int base = start + threadIdx.x * 8;
  for (; base + 8 <= end; base += 2048) {
    uint4 wv = *(const uint4*)(row + base);
    float4 r0 = *(const float4*)&rmn[base];
    float4 r1 = *(const float4*)&rmn[base + 4];
    float f0 = bf2f((unsigned short)(wv.x & 0xffff)) * r0.x;
    float f1 = bf2f((unsigned short)(wv.x >> 16)) * r0.y;
    float f2 = bf2f((unsigned short)(wv.y & 0xffff)) * r0.z;
    float f3 = bf2f((unsigned short)(wv.y >> 16)) * r0.w;
    float f4 = bf2f((unsigned short)(wv.z & 0xffff)) * r1.x;
    float f5 = bf2f((unsigned short)(wv.z >> 16)) * r1.y;
    float f6 = bf2f((unsigned short)(wv.w & 0xffff)) * r1.z;
    float f7 = bf2f((unsigned short)(wv.w >> 16)) * r1.w;
    insert_topL<8>(tv, ti, f0, base + 0);
    insert_topL<8>(tv, ti, f1, base + 1);
    insert_topL<8>(tv, ti, f2, base + 2);
    insert_topL<8>(tv, ti, f3, base + 3);
    insert_topL<8>(tv, ti, f4, base + 4);
    insert_topL<8>(tv, ti, f5, base + 5);
    insert_topL<8>(tv, ti, f6, base + 6);
    insert_topL<8>(tv, ti, f7, base + 7);
  }
  // ragged tail
  if (base < end) {
    for (int n = base; n < end; ++n)
      insert_topL<8>(tv, ti, bf2f(row[n]) * rmn[n], n);
  }
  int* dst = cand + (size_t)q * NCAND + c * TPC;
  block_extract<8>(tv, ti, TPC, [&](int r, float v, int i) {
    dst[r] = (i == 0x7fffffff) ? 0 : i;
  });
}

// ---------------- rescore candidates in fp32, final top-16 ----------------
__global__ __launch_bounds__(512) void rescore(
    const float* __restrict__ Q, const float* __restrict__ M,
    const float* __restrict__ qn, const int* __restrict__ cand,
    float* __restrict__ out, int N) {
  __shared__ float cosv[NCAND];
  __shared__ int cidx[NCAND];
  int q = blockIdx.x;
  int wave = threadIdx.x >> 6, lane = threadIdx.x & 63;
  const float4* qf4 = (const float4*)(Q + (size_t)q * DDIM);
  float4 qv[4];
#pragma unroll
  for (int t = 0; t < 4; ++t) qv[t] = qf4[t * 64 + lane];
  float qnv = qn[q];
#pragma unroll 1
  for (int i = 0; i < NCAND / 8; ++i) {
    int c = wave * (NCAND / 8) + i;
    int idx = cand[(size_t)q * NCAND + c];
    if (idx < 0 || idx >= N) idx = 0;
    const float4* mf4 = (const float4*)(M + (size_t)idx * DDIM);
    float dot = 0.f, sq = 0.f;
#pragma unroll
    for (int t = 0; t < 4; ++t) {
      float4 m = mf4[t * 64 + lane];
      dot += m.x * qv[t].x + m.y * qv[t].y + m.z * qv[t].z + m.w * qv[t].w;
      sq += m.x * m.x + m.y * m.y + m.z * m.z + m.w * m.w;
    }
#pragma unroll
    for (int o = 32; o > 0; o >>= 1) {
      dot += __shfl_down(dot, o, 64);
      sq += __shfl_down(sq, o, 64);
    }
    if (lane == 0) {
      cosv[c] = dot / fmaxf(qnv * sqrtf(sq), EPSV);
      cidx[c] = idx;
    }
  }
  __syncthreads();
  if (wave == 0) {
    float v0 = cosv[lane], v1 = cosv[lane + 64];
    int i0 = cidx[lane], i1 = cidx[lane + 64];
    for (int r = 0; r < 16; ++r) {
      bool fb = better(v0, i0, v1, i1);
      float bv = fb ? v0 : v1;
      int bi = fb ? i0 : i1;
      int bs = lane * 2 + (fb ? 0 : 1);
#pragma unroll
      for (int o = 32; o > 0; o >>= 1) {
        float ov = __shfl_down(bv, o, 64);
        int oi = __shfl_down(bi, o, 64);
        int os = __shfl_down(bs, o, 64);
        if (better(ov, oi, bv, bi)) { bv = ov; bi = oi; bs = os; }
      }
      bv = __shfl(bv, 0, 64);
      bi = __shfl(bi, 0, 64);
      bs = __shfl(bs, 0, 64);
      if (lane == (bs >> 1)) {
        if (bs & 1) v1 = -INFINITY; else v0 = -INFINITY;
      }
      if (lane == 0) {
        out[(size_t)q * 16 + r] = bv;
        out[(size_t)BQ * 16 + (size_t)q * 16 + r] = (float)bi;
      }
    }
  }
}

extern "C" void kernel_launch(void* const* d_in, const int* in_sizes, int n_in,
                              void* d_out, int out_size, void* d_ws, size_t ws_size,
                              hipStream_t stream) {
  const float* Q = (const float*)d_in[0];
  const float* M = (const float*)d_in[1];
  int N = in_sizes[1] / DDIM;
  float* out = (float*)d_out;

  int nb = (N + 63) / 64;
  int Npitch = nb * 64;

  char* w = (char*)d_ws;
  size_t off = 0;
  auto alloc = [&](size_t bytes) {
    char* p = w + off;
    off = (off + bytes + 255) & ~(size_t)255;
    return p;
  };
  unsigned short* Qb = (unsigned short*)alloc((size_t)BQ * DDIM * 2);
  float* qn = (float*)alloc((size_t)BQ * 4);
  float* rmn = (float*)alloc((size_t)Npitch * 4);
  int* cand = (int*)alloc((size_t)BQ * NCAND * 4);
  unsigned short* sims = (unsigned short*)alloc((size_t)BQ * Npitch * 2);
  (void)ws_size;

  int Nc = (((N + CH - 1) / CH) + 7) & ~7;

  prep_q<<<BQ / 4, 256, 0, stream>>>(Q, Qb, qn);
  gemm_topk<<<nb, 256, 0, stream>>>(M, Qb, sims, rmn, N, Npitch);
  select_chunks<<<dim3(CH, BQ), 256, 0, stream>>>(sims, rmn, cand, N, Npitch, Nc);
  rescore<<<BQ, 512, 0, stream>>>(Q, M, qn, cand, out, N);
}